// Round 2
// baseline (2216.891 us; speedup 1.0000x reference)
//
#include <hip/hip_runtime.h>
#include <math.h>

// VICRegL loss, MI355X. Key identities used:
//  - vicreg(a,b)==vicreg(b,a)  -> global term = vicreg(zg0,zg1)
//  - local_loss(z1,z0,...)==local_loss(z0,z1,...) -> compute once
//  - sum(cov^2) = ||Yc Yc^T||_F^2/(n-1)^2 (trace trick) for global (n=256 << d=8192)
//  - local cov via Gram G=X^T X (d=1024 side), centered analytically with col means

namespace {
constexpr float KLAMBDA = 25.0f, KMU = 25.0f, KNU = 1.0f, KALPHA = 0.75f, KEPS = 1e-4f;
constexpr int B = 256, D = 8192, N = 256, C = 1024, M = 20;
constexpr int NP = B * M;  // 5120 selected rows per pair

// workspace layout (in 4-byte words)
constexpr int W_SCAL = 0;                       // 64 scalars
constexpr int W_MUG  = 64;                      // global col sums -> means [2][D]
constexpr int W_QG   = W_MUG + 2 * D;           // global col sumsq [2][D]
constexpr int W_P    = W_QG + 2 * D;            // global centered row-gram [2][256*256]
constexpr int W_RMV  = W_P + 2 * 256 * 256;     // feat row-min partial [B][2][N]
constexpr int W_RMI  = W_RMV + 2 * B * N;
constexpr int W_CMV  = W_RMI + 2 * B * N;       // feat col-min partial [B][2][N]
constexpr int W_CMI  = W_CMV + 2 * B * N;
constexpr int W_SEL  = W_CMI + 2 * B * N;       // selected row ids [4][NP]
constexpr int W_MAT  = W_SEL + 4 * NP;          // matched row ids  [4][NP]
constexpr int W_CSUM = W_MAT + 4 * NP;          // per-matrix col sums [8][C]
constexpr int W_CSSQ = W_CSUM + 8 * C;          // per-matrix col sumsq [8][C]
constexpr int W_G    = W_CSSQ + 8 * C;          // local gram tiles [8][36][128][128]
constexpr int W_END  = W_G + 8 * 36 * 128 * 128;

enum { S_INVG = 0, S_VARG, S_DSQG, S_PSUM, S_COVL, S_INVL };
}  // namespace

__device__ __forceinline__ float block_reduce_sum(float v) {
  __shared__ float red[256];
  const int t = threadIdx.x;
  red[t] = v;
  __syncthreads();
  for (int s = 128; s > 0; s >>= 1) {
    if (t < s) red[t] += red[t + s];
    __syncthreads();
  }
  float r = red[0];
  __syncthreads();
  return r;
}

// ---------- K1a: global column sums/sumsq + invariance term ----------
__global__ __launch_bounds__(256) void k1a_gstats(const float* __restrict__ zg0,
                                                  const float* __restrict__ zg1,
                                                  float* __restrict__ ws) {
  const int j = blockIdx.x * 256 + threadIdx.x;   // column
  const int r0 = blockIdx.y * 32;                 // row chunk
  float s0 = 0, q0 = 0, s1 = 0, q1 = 0, sd = 0;
  for (int n = r0; n < r0 + 32; ++n) {
    float a = zg0[(size_t)n * D + j];
    float b = zg1[(size_t)n * D + j];
    s0 += a; q0 += a * a; s1 += b; q1 += b * b;
    float d = a - b; sd += d * d;
  }
  atomicAdd(&ws[W_MUG + j], s0);
  atomicAdd(&ws[W_MUG + D + j], s1);
  atomicAdd(&ws[W_QG + j], q0);
  atomicAdd(&ws[W_QG + D + j], q1);
  float t1 = block_reduce_sum(sd);
  if (threadIdx.x == 0) atomicAdd(&ws[W_SCAL + S_INVG], t1);
}

// ---------- K1b: finalize means, var_term + diag^2 for global ----------
__global__ __launch_bounds__(256) void k1b_gfinal(float* __restrict__ ws) {
  const int j = blockIdx.x * 256 + threadIdx.x;  // 0..8191
  float s0 = ws[W_MUG + j], s1 = ws[W_MUG + D + j];
  float q0 = ws[W_QG + j], q1 = ws[W_QG + D + j];
  ws[W_MUG + j] = s0 * (1.f / 256.f);
  ws[W_MUG + D + j] = s1 * (1.f / 256.f);
  float v0 = (q0 - s0 * s0 * (1.f / 256.f)) * (1.f / 255.f);
  float v1 = (q1 - s1 * s1 * (1.f / 256.f)) * (1.f / 255.f);
  float relu = fmaxf(0.f, 1.f - sqrtf(v0 + KEPS)) + fmaxf(0.f, 1.f - sqrtf(v1 + KEPS));
  float dsq = v0 * v0 + v1 * v1;
  float t2 = block_reduce_sum(relu);
  float t3 = block_reduce_sum(dsq);
  if (threadIdx.x == 0) {
    atomicAdd(&ws[W_SCAL + S_VARG], t2);
    atomicAdd(&ws[W_SCAL + S_DSQG], t3);
  }
}

// ---------- K2: global centered row-gram P = Yc Yc^T (K-split, atomics) ----------
__global__ __launch_bounds__(256) void k2_ggram(const float* __restrict__ zg0,
                                                const float* __restrict__ zg1,
                                                float* __restrict__ ws) {
  const int v = blockIdx.z;
  const float* zg = v ? zg1 : zg0;
  const float* mu = ws + W_MUG + v * D;
  float* P = ws + W_P + v * 65536;
  const int n0 = (blockIdx.x & 1) * 128, m0 = (blockIdx.x >> 1) * 128;
  const int kbase = blockIdx.y * 256;
  __shared__ float SM[2 * 32 * 132];
  __shared__ float mul[32];
  float (*Al)[132] = (float(*)[132])SM;
  float (*Bl)[132] = (float(*)[132])(SM + 32 * 132);
  const int t = threadIdx.x, tx = t & 15, ty = t >> 4;
  float acc[8][8] = {};
  for (int kc = 0; kc < 256; kc += 32) {
    const int k0 = kbase + kc;
    __syncthreads();
    if (t < 32) mul[t] = mu[k0 + t];
    __syncthreads();
#pragma unroll
    for (int j = 0; j < 4; ++j) {
      int f = t + 256 * j;
      int nn = f >> 3, kv = (f & 7) * 4;
      float4 a = *(const float4*)&zg[(size_t)(n0 + nn) * D + k0 + kv];
      Al[kv + 0][nn] = a.x - mul[kv + 0];
      Al[kv + 1][nn] = a.y - mul[kv + 1];
      Al[kv + 2][nn] = a.z - mul[kv + 2];
      Al[kv + 3][nn] = a.w - mul[kv + 3];
      float4 bb = *(const float4*)&zg[(size_t)(m0 + nn) * D + k0 + kv];
      Bl[kv + 0][nn] = bb.x - mul[kv + 0];
      Bl[kv + 1][nn] = bb.y - mul[kv + 1];
      Bl[kv + 2][nn] = bb.z - mul[kv + 2];
      Bl[kv + 3][nn] = bb.w - mul[kv + 3];
    }
    __syncthreads();
#pragma unroll 4
    for (int kk = 0; kk < 32; ++kk) {
      float4 x0 = *(const float4*)&Al[kk][ty * 8];
      float4 x1 = *(const float4*)&Al[kk][ty * 8 + 4];
      float4 y0 = *(const float4*)&Bl[kk][tx * 8];
      float4 y1 = *(const float4*)&Bl[kk][tx * 8 + 4];
      float av[8] = {x0.x, x0.y, x0.z, x0.w, x1.x, x1.y, x1.z, x1.w};
      float bv[8] = {y0.x, y0.y, y0.z, y0.w, y1.x, y1.y, y1.z, y1.w};
#pragma unroll
      for (int r = 0; r < 8; ++r)
#pragma unroll
        for (int c = 0; c < 8; ++c) acc[r][c] = fmaf(av[r], bv[c], acc[r][c]);
    }
  }
#pragma unroll
  for (int r = 0; r < 8; ++r)
#pragma unroll
    for (int c = 0; c < 8; ++c)
      atomicAdd(&P[(n0 + ty * 8 + r) * 256 + m0 + tx * 8 + c], acc[r][c]);
}

// ---------- K2b: PSUM = sum P^2 (both tensors) ----------
__global__ __launch_bounds__(256) void k2b_psum(float* __restrict__ ws) {
  float s = 0.f;
  for (int i = blockIdx.x * 256 + threadIdx.x; i < 2 * 65536; i += gridDim.x * 256) {
    float p = ws[W_P + i];
    s += p * p;
  }
  s = block_reduce_sum(s);
  if (threadIdx.x == 0) atomicAdd(&ws[W_SCAL + S_PSUM], s);
}

// ---------- K3: per-batch feature distance + fused row/col argmin ----------
__global__ __launch_bounds__(256) void k3_dist(const float* __restrict__ zl0,
                                               const float* __restrict__ zl1,
                                               float* __restrict__ ws) {
  const int b = blockIdx.y;
  const int ti = blockIdx.x & 1, tj = blockIdx.x >> 1;
  const float* za = zl0 + (size_t)b * N * C;
  const float* zb = zl1 + (size_t)b * N * C;
  const int n0 = ti * 128, m0 = tj * 128;
  __shared__ float SM[2 * 32 * 132];
  __shared__ float qa[128], qb[128];
  float (*Al)[132] = (float(*)[132])SM;
  float (*Bl)[132] = (float(*)[132])(SM + 32 * 132);
  const int t = threadIdx.x, tx = t & 15, ty = t >> 4, lane = t & 63;
  if (t < 128) { qa[t] = 0.f; qb[t] = 0.f; }
  float acc[8][8] = {};
  for (int k0 = 0; k0 < C; k0 += 32) {
    __syncthreads();
#pragma unroll
    for (int j = 0; j < 4; ++j) {
      int f = t + 256 * j;
      int nn = f >> 3, kv = (f & 7) * 4;
      float4 a = *(const float4*)&za[(size_t)(n0 + nn) * C + k0 + kv];
      Al[kv + 0][nn] = a.x; Al[kv + 1][nn] = a.y; Al[kv + 2][nn] = a.z; Al[kv + 3][nn] = a.w;
      float sa = a.x * a.x + a.y * a.y + a.z * a.z + a.w * a.w;
      sa += __shfl_xor(sa, 1); sa += __shfl_xor(sa, 2); sa += __shfl_xor(sa, 4);
      if ((lane & 7) == 0) qa[nn] += sa;
      float4 bb = *(const float4*)&zb[(size_t)(m0 + nn) * C + k0 + kv];
      Bl[kv + 0][nn] = bb.x; Bl[kv + 1][nn] = bb.y; Bl[kv + 2][nn] = bb.z; Bl[kv + 3][nn] = bb.w;
      float sb = bb.x * bb.x + bb.y * bb.y + bb.z * bb.z + bb.w * bb.w;
      sb += __shfl_xor(sb, 1); sb += __shfl_xor(sb, 2); sb += __shfl_xor(sb, 4);
      if ((lane & 7) == 0) qb[nn] += sb;
    }
    __syncthreads();
#pragma unroll 4
    for (int kk = 0; kk < 32; ++kk) {
      float4 x0 = *(const float4*)&Al[kk][ty * 8];
      float4 x1 = *(const float4*)&Al[kk][ty * 8 + 4];
      float4 y0 = *(const float4*)&Bl[kk][tx * 8];
      float4 y1 = *(const float4*)&Bl[kk][tx * 8 + 4];
      float av[8] = {x0.x, x0.y, x0.z, x0.w, x1.x, x1.y, x1.z, x1.w};
      float bv[8] = {y0.x, y0.y, y0.z, y0.w, y1.x, y1.y, y1.z, y1.w};
#pragma unroll
      for (int r = 0; r < 8; ++r)
#pragma unroll
        for (int c = 0; c < 8; ++c) acc[r][c] = fmaf(av[r], bv[c], acc[r][c]);
    }
  }
  __syncthreads();
  // row mins (a->b): reduce over tx within 16-lane groups
  for (int r = 0; r < 8; ++r) {
    float qan = qa[ty * 8 + r];
    float best = 3.4e38f; int bi = 0;
#pragma unroll
    for (int c = 0; c < 8; ++c) {
      float d2 = qan + qb[tx * 8 + c] - 2.f * acc[r][c];
      if (d2 < best) { best = d2; bi = m0 + tx * 8 + c; }
    }
#pragma unroll
    for (int mm = 8; mm >= 1; mm >>= 1) {
      float ov = __shfl_xor(best, mm); int oi = __shfl_xor(bi, mm);
      if (ov < best || (ov == best && oi < bi)) { best = ov; bi = oi; }
    }
    if (tx == 0) {
      int n = n0 + ty * 8 + r;
      ws[W_RMV + ((size_t)b * 2 + tj) * N + n] = best;
      ((int*)ws)[W_RMI + (b * 2 + tj) * N + n] = bi;
    }
  }
  // col mins (b->a): via LDS (reuse SM)
  float* cval = SM;
  int* cidx = (int*)(SM + 16 * 128);
  for (int c = 0; c < 8; ++c) {
    float qbm = qb[tx * 8 + c];
    float best = 3.4e38f; int bi = 0;
#pragma unroll
    for (int r = 0; r < 8; ++r) {
      float d2 = qa[ty * 8 + r] + qbm - 2.f * acc[r][c];
      if (d2 < best) { best = d2; bi = n0 + ty * 8 + r; }
    }
    cval[ty * 128 + tx * 8 + c] = best;
    cidx[ty * 128 + tx * 8 + c] = bi;
  }
  __syncthreads();
  if (t < 128) {
    float best = 3.4e38f; int bi = 0;
    for (int g = 0; g < 16; ++g) {
      float v = cval[g * 128 + t]; int i = cidx[g * 128 + t];
      if (v < best || (v == best && i < bi)) { best = v; bi = i; }
    }
    ws[W_CMV + ((size_t)b * 2 + ti) * N + m0 + t] = best;
    ((int*)ws)[W_CMI + (b * 2 + ti) * N + m0 + t] = bi;
  }
}

// ---------- K4: per-batch NN finalize + grid NN + top-20 selection ----------
__global__ __launch_bounds__(256) void k4_select(const float* __restrict__ gr0,
                                                 const float* __restrict__ gr1,
                                                 float* __restrict__ ws) {
  const int b = blockIdx.x, t = threadIdx.x;
  __shared__ float mdA[256], mdB[256], gmdA[256], gmdB[256];
  __shared__ int nnA[256], nnB[256], gnnA[256], gnnB[256];
  __shared__ float gx0[256], gy0[256], gx1[256], gy1[256];
  {
    float v0 = ws[W_RMV + ((size_t)b * 2 + 0) * N + t];
    int i0 = ((int*)ws)[W_RMI + (b * 2 + 0) * N + t];
    float v1 = ws[W_RMV + ((size_t)b * 2 + 1) * N + t];
    int i1 = ((int*)ws)[W_RMI + (b * 2 + 1) * N + t];
    if (v1 < v0 || (v1 == v0 && i1 < i0)) { v0 = v1; i0 = i1; }
    mdA[t] = v0; nnA[t] = i0;
    v0 = ws[W_CMV + ((size_t)b * 2 + 0) * N + t];
    i0 = ((int*)ws)[W_CMI + (b * 2 + 0) * N + t];
    v1 = ws[W_CMV + ((size_t)b * 2 + 1) * N + t];
    i1 = ((int*)ws)[W_CMI + (b * 2 + 1) * N + t];
    if (v1 < v0 || (v1 == v0 && i1 < i0)) { v0 = v1; i0 = i1; }
    mdB[t] = v0; nnB[t] = i0;
    gx0[t] = gr0[(size_t)b * 512 + t * 2 + 0];
    gy0[t] = gr0[(size_t)b * 512 + t * 2 + 1];
    gx1[t] = gr1[(size_t)b * 512 + t * 2 + 0];
    gy1[t] = gr1[(size_t)b * 512 + t * 2 + 1];
  }
  __syncthreads();
  {
    float px = gx0[t], py = gy0[t], best = 3.4e38f; int bi = 0;
    for (int mm = 0; mm < 256; ++mm) {
      float dx = px - gx1[mm], dy = py - gy1[mm];
      float d = dx * dx + dy * dy;
      if (d < best) { best = d; bi = mm; }
    }
    gmdA[t] = best; gnnA[t] = bi;
    px = gx1[t]; py = gy1[t]; best = 3.4e38f; bi = 0;
    for (int nn2 = 0; nn2 < 256; ++nn2) {
      float dx = px - gx0[nn2], dy = py - gy0[nn2];
      float d = dx * dx + dy * dy;
      if (d < best) { best = d; bi = nn2; }
    }
    gmdB[t] = best; gnnB[t] = bi;
  }
  __syncthreads();
  const int w = t >> 6, lane = t & 63;
  float* vals = (w == 0) ? mdA : (w == 1) ? mdB : (w == 2) ? gmdA : gmdB;
  int* nns = (w == 0) ? nnA : (w == 1) ? nnB : (w == 2) ? gnnA : gnnB;
  for (int k = 0; k < M; ++k) {
    float best = 3.4e38f; int bi = 1 << 30;
    for (int i = lane; i < 256; i += 64) {
      float v = vals[i];
      if (v < best || (v == best && i < bi)) { best = v; bi = i; }
    }
#pragma unroll
    for (int mm = 32; mm >= 1; mm >>= 1) {
      float ov = __shfl_xor(best, mm); int oi = __shfl_xor(bi, mm);
      if (ov < best || (ov == best && oi < bi)) { best = ov; bi = oi; }
    }
    if (lane == 0) {
      ((int*)ws)[W_SEL + w * NP + b * M + k] = b * 256 + bi;
      ((int*)ws)[W_MAT + w * NP + b * M + k] = b * 256 + nns[bi];
      vals[bi] = 3.4e38f;
    }
    __syncthreads();
  }
}

// ---------- K5: gathered pair stats: invariance + col sums/sumsq ----------
__global__ __launch_bounds__(256) void k5_pairstats(const float* __restrict__ zl0,
                                                    const float* __restrict__ zl1,
                                                    float* __restrict__ ws) {
  const int p = blockIdx.y, t = threadIdx.x;
  const float* X = (p & 1) ? zl1 : zl0;
  const float* Y = (p & 1) ? zl0 : zl1;
  const int* selR = (const int*)ws + W_SEL + p * NP;
  const int* matR = (const int*)ws + W_MAT + p * NP;
  const int r0 = blockIdx.x * 128;
  float sX[4] = {}, qX[4] = {}, sY[4] = {}, qY[4] = {};
  float inv = 0.f;
  for (int r = 0; r < 128; ++r) {
    const float* xr = X + (size_t)selR[r0 + r] * C;
    const float* yr = Y + (size_t)matR[r0 + r] * C;
#pragma unroll
    for (int j = 0; j < 4; ++j) {
      float x = xr[t + 256 * j], y = yr[t + 256 * j];
      sX[j] += x; qX[j] += x * x; sY[j] += y; qY[j] += y * y;
      float d = x - y; inv += d * d;
    }
  }
#pragma unroll
  for (int j = 0; j < 4; ++j) {
    atomicAdd(&ws[W_CSUM + (2 * p) * C + t + 256 * j], sX[j]);
    atomicAdd(&ws[W_CSSQ + (2 * p) * C + t + 256 * j], qX[j]);
    atomicAdd(&ws[W_CSUM + (2 * p + 1) * C + t + 256 * j], sY[j]);
    atomicAdd(&ws[W_CSSQ + (2 * p + 1) * C + t + 256 * j], qY[j]);
  }
  float s = block_reduce_sum(inv);
  if (t == 0) atomicAdd(&ws[W_SCAL + S_INVL], s);
}

// ---------- K6a: local Grams (8 matrices, upper 128x128 tiles, K-split 4) ----------
__global__ __launch_bounds__(256) void k6a_gram(const float* __restrict__ zl0,
                                                const float* __restrict__ zl1,
                                                float* __restrict__ ws) {
  const int m = blockIdx.y, p = m >> 1, isY = m & 1;
  const float* S = (((p & 1) ^ isY) != 0) ? zl1 : zl0;
  const int* rows = (const int*)ws + (isY ? W_MAT : W_SEL) + p * NP;
  int tti = 0, rem = blockIdx.x;
  while (rem >= 8 - tti) { rem -= 8 - tti; ++tti; }
  const int ttj = tti + rem;
  const int i0 = tti * 128, j0 = ttj * 128;
  const int kstart = blockIdx.z * 1280;
  __shared__ float SM[2 * 32 * 132];
  __shared__ int rr[32];
  float (*Al)[132] = (float(*)[132])SM;
  float (*Bl)[132] = (float(*)[132])(SM + 32 * 132);
  const int t = threadIdx.x, tx = t & 15, ty = t >> 4;
  float acc[8][8] = {};
  for (int k0 = kstart; k0 < kstart + 1280; k0 += 32) {
    __syncthreads();
    if (t < 32) rr[t] = rows[k0 + t];
    __syncthreads();
#pragma unroll
    for (int j = 0; j < 4; ++j) {
      int f = t + 256 * j;
      int kk = f >> 5, cv = (f & 31) * 4;
      const float* rp = S + (size_t)rr[kk] * C;
      *(float4*)&Al[kk][cv] = *(const float4*)&rp[i0 + cv];
      *(float4*)&Bl[kk][cv] = *(const float4*)&rp[j0 + cv];
    }
    __syncthreads();
#pragma unroll 4
    for (int kk = 0; kk < 32; ++kk) {
      float4 x0 = *(const float4*)&Al[kk][ty * 8];
      float4 x1 = *(const float4*)&Al[kk][ty * 8 + 4];
      float4 y0 = *(const float4*)&Bl[kk][tx * 8];
      float4 y1 = *(const float4*)&Bl[kk][tx * 8 + 4];
      float av[8] = {x0.x, x0.y, x0.z, x0.w, x1.x, x1.y, x1.z, x1.w};
      float bv[8] = {y0.x, y0.y, y0.z, y0.w, y1.x, y1.y, y1.z, y1.w};
#pragma unroll
      for (int r = 0; r < 8; ++r)
#pragma unroll
        for (int c = 0; c < 8; ++c) acc[r][c] = fmaf(av[r], bv[c], acc[r][c]);
    }
  }
  float* G = ws + W_G + ((size_t)m * 36 + blockIdx.x) * 16384;
#pragma unroll
  for (int r = 0; r < 8; ++r)
#pragma unroll
    for (int c = 0; c < 8; ++c)
      atomicAdd(&G[(ty * 8 + r) * 128 + tx * 8 + c], acc[r][c]);
}

// ---------- K6b: centered off-diag cov^2 reduce over Gram tiles ----------
__global__ __launch_bounds__(256) void k6b_covred(float* __restrict__ ws) {
  const int m = blockIdx.y;
  int tti = 0, rem = blockIdx.x;
  while (rem >= 8 - tti) { rem -= 8 - tti; ++tti; }
  const int ttj = tti + rem;
  const int i0 = tti * 128, j0 = ttj * 128;
  const float* G = ws + W_G + ((size_t)m * 36 + blockIdx.x) * 16384;
  const float* cs = ws + W_CSUM + m * C;
  const int t = threadIdx.x;
  float lsum = 0.f;
  for (int i = 0; i < 64; ++i) {
    int e = i * 256 + t;
    int r = e >> 7, c = e & 127;
    int gi = i0 + r, gj = j0 + c;
    if (gi != gj) {
      float mui = cs[gi] * (1.f / 5120.f);
      float muj = cs[gj] * (1.f / 5120.f);
      float cv = (G[e] - 5120.f * mui * muj) * (1.f / 5119.f);
      lsum += cv * cv;
    }
  }
  lsum *= (tti == ttj) ? 1.f : 2.f;  // off-diag tiles stand for both (i,j) and (j,i)
  float s = block_reduce_sum(lsum);
  if (t == 0) atomicAdd(&ws[W_SCAL + S_COVL], s);
}

// ---------- K7: final combine ----------
__global__ __launch_bounds__(256) void k7_final(float* __restrict__ ws, float* __restrict__ out) {
  const int t = threadIdx.x;
  float rl = 0.f;
  for (int i = t; i < 8 * C; i += 256) {
    float s = ws[W_CSUM + i], q = ws[W_CSSQ + i];
    float var = (q - s * s * (1.f / 5120.f)) * (1.f / 5119.f);
    rl += fmaxf(0.f, 1.f - sqrtf(var + KEPS));
  }
  float varL = block_reduce_sum(rl);
  if (t == 0) {
    float invG = ws[W_SCAL + S_INVG] * (1.f / (256.f * 8192.f));
    float varG = ws[W_SCAL + S_VARG] * (1.f / 8192.f);
    float covG =
        (ws[W_SCAL + S_PSUM] * (1.f / (255.f * 255.f)) - ws[W_SCAL + S_DSQG]) * (1.f / 8192.f);
    float g = KLAMBDA * invG + KMU * 0.5f * varG + KNU * covG;
    float invL = ws[W_SCAL + S_INVL] * (1.f / ((float)NP * (float)C));
    float l = 0.5f * (KLAMBDA * invL + KMU * 0.5f * varL * (1.f / 1024.f) +
                      KNU * ws[W_SCAL + S_COVL] * (1.f / 1024.f));
    out[0] = KALPHA * g + (1.f - KALPHA) * l;
  }
}

extern "C" void kernel_launch(void* const* d_in, const int* in_sizes, int n_in,
                              void* d_out, int out_size, void* d_ws, size_t ws_size,
                              hipStream_t stream) {
  (void)in_sizes; (void)n_in; (void)out_size; (void)ws_size;
  const float* zg0 = (const float*)d_in[0];
  const float* zg1 = (const float*)d_in[1];
  const float* zl0 = (const float*)d_in[2];
  const float* zl1 = (const float*)d_in[3];
  const float* gr0 = (const float*)d_in[4];
  const float* gr1 = (const float*)d_in[5];
  float* ws = (float*)d_ws;
  float* out = (float*)d_out;

  hipMemsetAsync(d_ws, 0, (size_t)W_END * 4, stream);
  hipLaunchKernelGGL(k1a_gstats, dim3(32, 8), dim3(256), 0, stream, zg0, zg1, ws);
  hipLaunchKernelGGL(k1b_gfinal, dim3(32), dim3(256), 0, stream, ws);
  hipLaunchKernelGGL(k2_ggram, dim3(4, 32, 2), dim3(256), 0, stream, zg0, zg1, ws);
  hipLaunchKernelGGL(k2b_psum, dim3(128), dim3(256), 0, stream, ws);
  hipLaunchKernelGGL(k3_dist, dim3(4, 256), dim3(256), 0, stream, zl0, zl1, ws);
  hipLaunchKernelGGL(k4_select, dim3(256), dim3(256), 0, stream, gr0, gr1, ws);
  hipLaunchKernelGGL(k5_pairstats, dim3(40, 4), dim3(256), 0, stream, zl0, zl1, ws);
  hipLaunchKernelGGL(k6a_gram, dim3(36, 8, 4), dim3(256), 0, stream, zl0, zl1, ws);
  hipLaunchKernelGGL(k6b_covred, dim3(36, 8), dim3(256), 0, stream, ws);
  hipLaunchKernelGGL(k7_final, dim3(1), dim3(256), 0, stream, ws, out);
}

// Round 3
// 1269.362 us; speedup vs baseline: 1.7465x; 1.7465x over previous
//
#include <hip/hip_runtime.h>
#include <math.h>

// VICRegL loss, MI355X. Identities:
//  - vicreg(a,b)==vicreg(b,a)  -> global term = vicreg(zg0,zg1) once
//  - local_loss(z1,z0,...)==local_loss(z0,z1,...) -> compute once
//  - sum(cov^2) = ||Yc Yc^T||_F^2/(n-1)^2 (trace trick) for global
//  - local cov via Gram G=X^T X (d=1024 side), centered analytically
// Round 3: k3 (distance gram) and k6a (local grams) moved to bf16 MFMA
// (32x32x16), f32 row-norms/stats kept exact. k6a split-K 4 -> 2.

namespace {
constexpr float KLAMBDA = 25.0f, KMU = 25.0f, KNU = 1.0f, KALPHA = 0.75f, KEPS = 1e-4f;
constexpr int B = 256, D = 8192, N = 256, C = 1024, M = 20;
constexpr int NP = B * M;  // 5120 selected rows per pair
constexpr int PADK = 40;   // LDS row stride in bf16 elements (80 B, 16B-aligned)

// workspace layout (in 4-byte words)
constexpr int W_SCAL = 0;                       // 64 scalars
constexpr int W_MUG  = 64;                      // global col sums -> means [2][D]
constexpr int W_QG   = W_MUG + 2 * D;           // global col sumsq [2][D]
constexpr int W_P    = W_QG + 2 * D;            // global centered row-gram [2][256*256]
constexpr int W_RMV  = W_P + 2 * 256 * 256;     // feat row-min partial [B][2][N]
constexpr int W_RMI  = W_RMV + 2 * B * N;
constexpr int W_CMV  = W_RMI + 2 * B * N;       // feat col-min partial [B][2][N]
constexpr int W_CMI  = W_CMV + 2 * B * N;
constexpr int W_SEL  = W_CMI + 2 * B * N;       // selected row ids [4][NP]
constexpr int W_MAT  = W_SEL + 4 * NP;          // matched row ids  [4][NP]
constexpr int W_CSUM = W_MAT + 4 * NP;          // per-matrix col sums [8][C]
constexpr int W_CSSQ = W_CSUM + 8 * C;          // per-matrix col sumsq [8][C]
constexpr int W_G    = W_CSSQ + 8 * C;          // local gram tiles [8][36][128][128]
constexpr int W_END  = W_G + 8 * 36 * 128 * 128;

enum { S_INVG = 0, S_VARG, S_DSQG, S_PSUM, S_COVL, S_INVL };
}  // namespace

typedef short bf16x8 __attribute__((ext_vector_type(8)));
typedef float f32x16 __attribute__((ext_vector_type(16)));

__device__ __forceinline__ unsigned int f2bf(float x) {
  union { float f; unsigned int u; } v;
  v.f = x;
  return (v.u + 0x7fffu + ((v.u >> 16) & 1u)) >> 16;  // RNE to bf16 bits
}

__device__ __forceinline__ float block_reduce_sum(float v) {
  __shared__ float red[256];
  const int t = threadIdx.x;
  red[t] = v;
  __syncthreads();
  for (int s = 128; s > 0; s >>= 1) {
    if (t < s) red[t] += red[t + s];
    __syncthreads();
  }
  float r = red[0];
  __syncthreads();
  return r;
}

// ---------- K1a: global column sums/sumsq + invariance term ----------
__global__ __launch_bounds__(256) void k1a_gstats(const float* __restrict__ zg0,
                                                  const float* __restrict__ zg1,
                                                  float* __restrict__ ws) {
  const int j = blockIdx.x * 256 + threadIdx.x;
  const int r0 = blockIdx.y * 32;
  float s0 = 0, q0 = 0, s1 = 0, q1 = 0, sd = 0;
  for (int n = r0; n < r0 + 32; ++n) {
    float a = zg0[(size_t)n * D + j];
    float b = zg1[(size_t)n * D + j];
    s0 += a; q0 += a * a; s1 += b; q1 += b * b;
    float d = a - b; sd += d * d;
  }
  atomicAdd(&ws[W_MUG + j], s0);
  atomicAdd(&ws[W_MUG + D + j], s1);
  atomicAdd(&ws[W_QG + j], q0);
  atomicAdd(&ws[W_QG + D + j], q1);
  float t1 = block_reduce_sum(sd);
  if (threadIdx.x == 0) atomicAdd(&ws[W_SCAL + S_INVG], t1);
}

// ---------- K1b: finalize means, var_term + diag^2 for global ----------
__global__ __launch_bounds__(256) void k1b_gfinal(float* __restrict__ ws) {
  const int j = blockIdx.x * 256 + threadIdx.x;
  float s0 = ws[W_MUG + j], s1 = ws[W_MUG + D + j];
  float q0 = ws[W_QG + j], q1 = ws[W_QG + D + j];
  ws[W_MUG + j] = s0 * (1.f / 256.f);
  ws[W_MUG + D + j] = s1 * (1.f / 256.f);
  float v0 = (q0 - s0 * s0 * (1.f / 256.f)) * (1.f / 255.f);
  float v1 = (q1 - s1 * s1 * (1.f / 256.f)) * (1.f / 255.f);
  float relu = fmaxf(0.f, 1.f - sqrtf(v0 + KEPS)) + fmaxf(0.f, 1.f - sqrtf(v1 + KEPS));
  float dsq = v0 * v0 + v1 * v1;
  float t2 = block_reduce_sum(relu);
  float t3 = block_reduce_sum(dsq);
  if (threadIdx.x == 0) {
    atomicAdd(&ws[W_SCAL + S_VARG], t2);
    atomicAdd(&ws[W_SCAL + S_DSQG], t3);
  }
}

// ---------- K2: global centered row-gram P = Yc Yc^T (f32 VALU, small) ----------
__global__ __launch_bounds__(256) void k2_ggram(const float* __restrict__ zg0,
                                                const float* __restrict__ zg1,
                                                float* __restrict__ ws) {
  const int v = blockIdx.z;
  const float* zg = v ? zg1 : zg0;
  const float* mu = ws + W_MUG + v * D;
  float* P = ws + W_P + v * 65536;
  const int n0 = (blockIdx.x & 1) * 128, m0 = (blockIdx.x >> 1) * 128;
  const int kbase = blockIdx.y * 256;
  __shared__ float SM[2 * 32 * 132];
  __shared__ float mul[32];
  float (*Al)[132] = (float(*)[132])SM;
  float (*Bl)[132] = (float(*)[132])(SM + 32 * 132);
  const int t = threadIdx.x, tx = t & 15, ty = t >> 4;
  float acc[8][8] = {};
  for (int kc = 0; kc < 256; kc += 32) {
    const int k0 = kbase + kc;
    __syncthreads();
    if (t < 32) mul[t] = mu[k0 + t];
    __syncthreads();
#pragma unroll
    for (int j = 0; j < 4; ++j) {
      int f = t + 256 * j;
      int nn = f >> 3, kv = (f & 7) * 4;
      float4 a = *(const float4*)&zg[(size_t)(n0 + nn) * D + k0 + kv];
      Al[kv + 0][nn] = a.x - mul[kv + 0];
      Al[kv + 1][nn] = a.y - mul[kv + 1];
      Al[kv + 2][nn] = a.z - mul[kv + 2];
      Al[kv + 3][nn] = a.w - mul[kv + 3];
      float4 bb = *(const float4*)&zg[(size_t)(m0 + nn) * D + k0 + kv];
      Bl[kv + 0][nn] = bb.x - mul[kv + 0];
      Bl[kv + 1][nn] = bb.y - mul[kv + 1];
      Bl[kv + 2][nn] = bb.z - mul[kv + 2];
      Bl[kv + 3][nn] = bb.w - mul[kv + 3];
    }
    __syncthreads();
#pragma unroll 4
    for (int kk = 0; kk < 32; ++kk) {
      float4 x0 = *(const float4*)&Al[kk][ty * 8];
      float4 x1 = *(const float4*)&Al[kk][ty * 8 + 4];
      float4 y0 = *(const float4*)&Bl[kk][tx * 8];
      float4 y1 = *(const float4*)&Bl[kk][tx * 8 + 4];
      float av[8] = {x0.x, x0.y, x0.z, x0.w, x1.x, x1.y, x1.z, x1.w};
      float bv[8] = {y0.x, y0.y, y0.z, y0.w, y1.x, y1.y, y1.z, y1.w};
#pragma unroll
      for (int r = 0; r < 8; ++r)
#pragma unroll
        for (int c = 0; c < 8; ++c) acc[r][c] = fmaf(av[r], bv[c], acc[r][c]);
    }
  }
#pragma unroll
  for (int r = 0; r < 8; ++r)
#pragma unroll
    for (int c = 0; c < 8; ++c)
      atomicAdd(&P[(n0 + ty * 8 + r) * 256 + m0 + tx * 8 + c], acc[r][c]);
}

// ---------- K2b: PSUM = sum P^2 ----------
__global__ __launch_bounds__(256) void k2b_psum(float* __restrict__ ws) {
  float s = 0.f;
  for (int i = blockIdx.x * 256 + threadIdx.x; i < 2 * 65536; i += gridDim.x * 256) {
    float p = ws[W_P + i];
    s += p * p;
  }
  s = block_reduce_sum(s);
  if (threadIdx.x == 0) atomicAdd(&ws[W_SCAL + S_PSUM], s);
}

// ---------- K3: per-batch feature distances via bf16 MFMA + fused argmins ----------
__global__ __launch_bounds__(256) void k3_dist(const float* __restrict__ zl0,
                                               const float* __restrict__ zl1,
                                               float* __restrict__ ws) {
  const int b = blockIdx.y;
  const int ti = blockIdx.x & 1, tj = blockIdx.x >> 1;
  const float* za = zl0 + (size_t)b * N * C + (size_t)ti * 128 * C;
  const float* zb = zl1 + (size_t)b * N * C + (size_t)tj * 128 * C;
  __shared__ unsigned short Al[128 * PADK], Bl[128 * PADK];
  __shared__ float qaf[2][128], qbf[2][128];
  __shared__ float rm2v[2][128], cm2v[2][128];
  __shared__ int rm2i[2][128], cm2i[2][128];
  const int t = threadIdx.x, w = t >> 6, l = t & 63;
  const int r = t & 127, half = t >> 7;
  const int hw = l >> 5, l31 = l & 31;
  f32x16 acc[2][2];
#pragma unroll
  for (int i = 0; i < 2; ++i)
#pragma unroll
    for (int j = 0; j < 2; ++j)
#pragma unroll
      for (int e = 0; e < 16; ++e) acc[i][j][e] = 0.f;
  float qacc = 0.f, qbacc = 0.f;
  for (int k0 = 0; k0 < C; k0 += 32) {
    __syncthreads();
    {
      const float* pa = za + (size_t)r * C + k0 + half * 16;
      float4 v0 = *(const float4*)(pa);
      float4 v1 = *(const float4*)(pa + 4);
      float4 v2 = *(const float4*)(pa + 8);
      float4 v3 = *(const float4*)(pa + 12);
      qacc += v0.x * v0.x + v0.y * v0.y + v0.z * v0.z + v0.w * v0.w;
      qacc += v1.x * v1.x + v1.y * v1.y + v1.z * v1.z + v1.w * v1.w;
      qacc += v2.x * v2.x + v2.y * v2.y + v2.z * v2.z + v2.w * v2.w;
      qacc += v3.x * v3.x + v3.y * v3.y + v3.z * v3.z + v3.w * v3.w;
      uint4 w0, w1;
      w0.x = f2bf(v0.x) | (f2bf(v0.y) << 16);
      w0.y = f2bf(v0.z) | (f2bf(v0.w) << 16);
      w0.z = f2bf(v1.x) | (f2bf(v1.y) << 16);
      w0.w = f2bf(v1.z) | (f2bf(v1.w) << 16);
      w1.x = f2bf(v2.x) | (f2bf(v2.y) << 16);
      w1.y = f2bf(v2.z) | (f2bf(v2.w) << 16);
      w1.z = f2bf(v3.x) | (f2bf(v3.y) << 16);
      w1.w = f2bf(v3.z) | (f2bf(v3.w) << 16);
      *(uint4*)&Al[r * PADK + half * 16] = w0;
      *(uint4*)&Al[r * PADK + half * 16 + 8] = w1;
      const float* pb = zb + (size_t)r * C + k0 + half * 16;
      v0 = *(const float4*)(pb);
      v1 = *(const float4*)(pb + 4);
      v2 = *(const float4*)(pb + 8);
      v3 = *(const float4*)(pb + 12);
      qbacc += v0.x * v0.x + v0.y * v0.y + v0.z * v0.z + v0.w * v0.w;
      qbacc += v1.x * v1.x + v1.y * v1.y + v1.z * v1.z + v1.w * v1.w;
      qbacc += v2.x * v2.x + v2.y * v2.y + v2.z * v2.z + v2.w * v2.w;
      qbacc += v3.x * v3.x + v3.y * v3.y + v3.z * v3.z + v3.w * v3.w;
      w0.x = f2bf(v0.x) | (f2bf(v0.y) << 16);
      w0.y = f2bf(v0.z) | (f2bf(v0.w) << 16);
      w0.z = f2bf(v1.x) | (f2bf(v1.y) << 16);
      w0.w = f2bf(v1.z) | (f2bf(v1.w) << 16);
      w1.x = f2bf(v2.x) | (f2bf(v2.y) << 16);
      w1.y = f2bf(v2.z) | (f2bf(v2.w) << 16);
      w1.z = f2bf(v3.x) | (f2bf(v3.y) << 16);
      w1.w = f2bf(v3.z) | (f2bf(v3.w) << 16);
      *(uint4*)&Bl[r * PADK + half * 16] = w0;
      *(uint4*)&Bl[r * PADK + half * 16 + 8] = w1;
    }
    __syncthreads();
#pragma unroll
    for (int ks = 0; ks < 2; ++ks) {
      const int koff = ks * 16 + hw * 8;
      bf16x8 a0 = *(const bf16x8*)&Al[((w >> 1) * 64 + l31) * PADK + koff];
      bf16x8 a1 = *(const bf16x8*)&Al[((w >> 1) * 64 + 32 + l31) * PADK + koff];
      bf16x8 b0 = *(const bf16x8*)&Bl[((w & 1) * 64 + l31) * PADK + koff];
      bf16x8 b1 = *(const bf16x8*)&Bl[((w & 1) * 64 + 32 + l31) * PADK + koff];
      acc[0][0] = __builtin_amdgcn_mfma_f32_32x32x16_bf16(a0, b0, acc[0][0], 0, 0, 0);
      acc[0][1] = __builtin_amdgcn_mfma_f32_32x32x16_bf16(a0, b1, acc[0][1], 0, 0, 0);
      acc[1][0] = __builtin_amdgcn_mfma_f32_32x32x16_bf16(a1, b0, acc[1][0], 0, 0, 0);
      acc[1][1] = __builtin_amdgcn_mfma_f32_32x32x16_bf16(a1, b1, acc[1][1], 0, 0, 0);
    }
  }
  __syncthreads();
  qaf[half][r] = qacc;
  qbf[half][r] = qbacc;
  __syncthreads();
  if (t < 128) { qaf[0][t] += qaf[1][t]; qbf[0][t] += qbf[1][t]; }
  __syncthreads();
  // row mins (over this tile's 128 cols)
#pragma unroll
  for (int fi = 0; fi < 2; ++fi) {
#pragma unroll
    for (int v = 0; v < 16; ++v) {
      const int il = (w >> 1) * 64 + fi * 32 + (v & 3) + ((v >> 2) << 3) + (hw << 2);
      const float qi = qaf[0][il];
      const int jb = tj * 128 + (w & 1) * 64;
      float d0 = qi + qbf[0][(w & 1) * 64 + l31] - 2.f * acc[fi][0][v];
      float d1 = qi + qbf[0][(w & 1) * 64 + 32 + l31] - 2.f * acc[fi][1][v];
      float best = d0; int bi = jb + l31;
      if (d1 < best) { best = d1; bi = jb + 32 + l31; }
#pragma unroll
      for (int mm = 16; mm >= 1; mm >>= 1) {
        float ov = __shfl_xor(best, mm);
        int oi = __shfl_xor(bi, mm);
        if (ov < best || (ov == best && oi < bi)) { best = ov; bi = oi; }
      }
      if (l31 == 0) { rm2v[w & 1][il] = best; rm2i[w & 1][il] = bi; }
    }
  }
  // col mins (over this tile's 128 rows)
#pragma unroll
  for (int fj = 0; fj < 2; ++fj) {
    const int jl = (w & 1) * 64 + fj * 32 + l31;
    const float qj = qbf[0][jl];
    float best = 3.4e38f; int bi = 1 << 30;
#pragma unroll
    for (int fi = 0; fi < 2; ++fi) {
#pragma unroll
      for (int v = 0; v < 16; ++v) {
        const int il = (w >> 1) * 64 + fi * 32 + (v & 3) + ((v >> 2) << 3) + (hw << 2);
        float d = qaf[0][il] + qj - 2.f * acc[fi][fj][v];
        int gi = ti * 128 + il;
        if (d < best || (d == best && gi < bi)) { best = d; bi = gi; }
      }
    }
    float ov = __shfl_xor(best, 32);
    int oi = __shfl_xor(bi, 32);
    if (ov < best || (ov == best && oi < bi)) { best = ov; bi = oi; }
    if (hw == 0) { cm2v[w >> 1][jl] = best; cm2i[w >> 1][jl] = bi; }
  }
  __syncthreads();
  if (t < 128) {
    float v0 = rm2v[0][t], v1 = rm2v[1][t];
    int i0 = rm2i[0][t], i1 = rm2i[1][t];
    if (v1 < v0 || (v1 == v0 && i1 < i0)) { v0 = v1; i0 = i1; }
    ws[W_RMV + ((size_t)b * 2 + tj) * N + ti * 128 + t] = v0;
    ((int*)ws)[W_RMI + (b * 2 + tj) * N + ti * 128 + t] = i0;
    v0 = cm2v[0][t]; v1 = cm2v[1][t];
    i0 = cm2i[0][t]; i1 = cm2i[1][t];
    if (v1 < v0 || (v1 == v0 && i1 < i0)) { v0 = v1; i0 = i1; }
    ws[W_CMV + ((size_t)b * 2 + ti) * N + tj * 128 + t] = v0;
    ((int*)ws)[W_CMI + (b * 2 + ti) * N + tj * 128 + t] = i0;
  }
}

// ---------- K4: per-batch NN finalize + grid NN + top-20 selection ----------
__global__ __launch_bounds__(256) void k4_select(const float* __restrict__ gr0,
                                                 const float* __restrict__ gr1,
                                                 float* __restrict__ ws) {
  const int b = blockIdx.x, t = threadIdx.x;
  __shared__ float mdA[256], mdB[256], gmdA[256], gmdB[256];
  __shared__ int nnA[256], nnB[256], gnnA[256], gnnB[256];
  __shared__ float gx0[256], gy0[256], gx1[256], gy1[256];
  {
    float v0 = ws[W_RMV + ((size_t)b * 2 + 0) * N + t];
    int i0 = ((int*)ws)[W_RMI + (b * 2 + 0) * N + t];
    float v1 = ws[W_RMV + ((size_t)b * 2 + 1) * N + t];
    int i1 = ((int*)ws)[W_RMI + (b * 2 + 1) * N + t];
    if (v1 < v0 || (v1 == v0 && i1 < i0)) { v0 = v1; i0 = i1; }
    mdA[t] = v0; nnA[t] = i0;
    v0 = ws[W_CMV + ((size_t)b * 2 + 0) * N + t];
    i0 = ((int*)ws)[W_CMI + (b * 2 + 0) * N + t];
    v1 = ws[W_CMV + ((size_t)b * 2 + 1) * N + t];
    i1 = ((int*)ws)[W_CMI + (b * 2 + 1) * N + t];
    if (v1 < v0 || (v1 == v0 && i1 < i0)) { v0 = v1; i0 = i1; }
    mdB[t] = v0; nnB[t] = i0;
    gx0[t] = gr0[(size_t)b * 512 + t * 2 + 0];
    gy0[t] = gr0[(size_t)b * 512 + t * 2 + 1];
    gx1[t] = gr1[(size_t)b * 512 + t * 2 + 0];
    gy1[t] = gr1[(size_t)b * 512 + t * 2 + 1];
  }
  __syncthreads();
  {
    float px = gx0[t], py = gy0[t], best = 3.4e38f; int bi = 0;
    for (int mm = 0; mm < 256; ++mm) {
      float dx = px - gx1[mm], dy = py - gy1[mm];
      float d = dx * dx + dy * dy;
      if (d < best) { best = d; bi = mm; }
    }
    gmdA[t] = best; gnnA[t] = bi;
    px = gx1[t]; py = gy1[t]; best = 3.4e38f; bi = 0;
    for (int nn2 = 0; nn2 < 256; ++nn2) {
      float dx = px - gx0[nn2], dy = py - gy0[nn2];
      float d = dx * dx + dy * dy;
      if (d < best) { best = d; bi = nn2; }
    }
    gmdB[t] = best; gnnB[t] = bi;
  }
  __syncthreads();
  const int w = t >> 6, lane = t & 63;
  float* vals = (w == 0) ? mdA : (w == 1) ? mdB : (w == 2) ? gmdA : gmdB;
  int* nns = (w == 0) ? nnA : (w == 1) ? nnB : (w == 2) ? gnnA : gnnB;
  for (int k = 0; k < M; ++k) {
    float best = 3.4e38f; int bi = 1 << 30;
    for (int i = lane; i < 256; i += 64) {
      float v = vals[i];
      if (v < best || (v == best && i < bi)) { best = v; bi = i; }
    }
#pragma unroll
    for (int mm = 32; mm >= 1; mm >>= 1) {
      float ov = __shfl_xor(best, mm);
      int oi = __shfl_xor(bi, mm);
      if (ov < best || (ov == best && oi < bi)) { best = ov; bi = oi; }
    }
    if (lane == 0) {
      ((int*)ws)[W_SEL + w * NP + b * M + k] = b * 256 + bi;
      ((int*)ws)[W_MAT + w * NP + b * M + k] = b * 256 + nns[bi];
      vals[bi] = 3.4e38f;
    }
    __syncthreads();
  }
}

// ---------- K5: gathered pair stats: invariance + col sums/sumsq ----------
__global__ __launch_bounds__(256) void k5_pairstats(const float* __restrict__ zl0,
                                                    const float* __restrict__ zl1,
                                                    float* __restrict__ ws) {
  const int p = blockIdx.y, t = threadIdx.x;
  const float* X = (p & 1) ? zl1 : zl0;
  const float* Y = (p & 1) ? zl0 : zl1;
  const int* selR = (const int*)ws + W_SEL + p * NP;
  const int* matR = (const int*)ws + W_MAT + p * NP;
  const int r0 = blockIdx.x * 128;
  float sX[4] = {}, qX[4] = {}, sY[4] = {}, qY[4] = {};
  float inv = 0.f;
  for (int r = 0; r < 128; ++r) {
    const float* xr = X + (size_t)selR[r0 + r] * C;
    const float* yr = Y + (size_t)matR[r0 + r] * C;
#pragma unroll
    for (int j = 0; j < 4; ++j) {
      float x = xr[t + 256 * j], y = yr[t + 256 * j];
      sX[j] += x; qX[j] += x * x; sY[j] += y; qY[j] += y * y;
      float d = x - y; inv += d * d;
    }
  }
#pragma unroll
  for (int j = 0; j < 4; ++j) {
    atomicAdd(&ws[W_CSUM + (2 * p) * C + t + 256 * j], sX[j]);
    atomicAdd(&ws[W_CSSQ + (2 * p) * C + t + 256 * j], qX[j]);
    atomicAdd(&ws[W_CSUM + (2 * p + 1) * C + t + 256 * j], sY[j]);
    atomicAdd(&ws[W_CSSQ + (2 * p + 1) * C + t + 256 * j], qY[j]);
  }
  float s = block_reduce_sum(inv);
  if (t == 0) atomicAdd(&ws[W_SCAL + S_INVL], s);
}

// ---------- K6a: local Grams via bf16 MFMA (write-side transposed staging) ----------
__global__ __launch_bounds__(256) void k6a_gram(const float* __restrict__ zl0,
                                                const float* __restrict__ zl1,
                                                float* __restrict__ ws) {
  const int mvar = blockIdx.y, p = mvar >> 1, isY = mvar & 1;
  const float* S = (((p & 1) ^ isY) != 0) ? zl1 : zl0;
  const int* rows = (const int*)ws + (isY ? W_MAT : W_SEL) + p * NP;
  int tti = 0, rem = blockIdx.x;
  while (rem >= 8 - tti) { rem -= 8 - tti; ++tti; }
  const int ttj = tti + rem;
  const int i0 = tti * 128, j0 = ttj * 128;
  const int kstart = blockIdx.z * 2560;
  __shared__ unsigned short Ta[128 * PADK], Tb[128 * PADK];
  __shared__ int rr[32];
  const int t = threadIdx.x, w = t >> 6, l = t & 63;
  const int hw = l >> 5, l31 = l & 31;
  const int kp2 = t >> 5;          // 0..7 (sample-pair group)
  const int c4 = (t & 31) * 4;     // column base 0..124
  f32x16 acc[2][2];
#pragma unroll
  for (int i = 0; i < 2; ++i)
#pragma unroll
    for (int j = 0; j < 2; ++j)
#pragma unroll
      for (int e = 0; e < 16; ++e) acc[i][j][e] = 0.f;
  for (int k0 = kstart; k0 < kstart + 2560; k0 += 32) {
    __syncthreads();
    if (t < 32) rr[t] = rows[k0 + t];
    __syncthreads();
#pragma unroll
    for (int rep = 0; rep < 2; ++rep) {
      const int k = (kp2 + rep * 8) * 2;  // even sample index 0..30
      const float* r0p = S + (size_t)rr[k] * C;
      const float* r1p = S + (size_t)rr[k + 1] * C;
      float4 a0 = *(const float4*)&r0p[i0 + c4];
      float4 a1 = *(const float4*)&r1p[i0 + c4];
      *(unsigned int*)&Ta[(c4 + 0) * PADK + k] = f2bf(a0.x) | (f2bf(a1.x) << 16);
      *(unsigned int*)&Ta[(c4 + 1) * PADK + k] = f2bf(a0.y) | (f2bf(a1.y) << 16);
      *(unsigned int*)&Ta[(c4 + 2) * PADK + k] = f2bf(a0.z) | (f2bf(a1.z) << 16);
      *(unsigned int*)&Ta[(c4 + 3) * PADK + k] = f2bf(a0.w) | (f2bf(a1.w) << 16);
      float4 b0v = *(const float4*)&r0p[j0 + c4];
      float4 b1v = *(const float4*)&r1p[j0 + c4];
      *(unsigned int*)&Tb[(c4 + 0) * PADK + k] = f2bf(b0v.x) | (f2bf(b1v.x) << 16);
      *(unsigned int*)&Tb[(c4 + 1) * PADK + k] = f2bf(b0v.y) | (f2bf(b1v.y) << 16);
      *(unsigned int*)&Tb[(c4 + 2) * PADK + k] = f2bf(b0v.z) | (f2bf(b1v.z) << 16);
      *(unsigned int*)&Tb[(c4 + 3) * PADK + k] = f2bf(b0v.w) | (f2bf(b1v.w) << 16);
    }
    __syncthreads();
#pragma unroll
    for (int ks = 0; ks < 2; ++ks) {
      const int koff = ks * 16 + hw * 8;
      bf16x8 a0 = *(const bf16x8*)&Ta[((w >> 1) * 64 + l31) * PADK + koff];
      bf16x8 a1 = *(const bf16x8*)&Ta[((w >> 1) * 64 + 32 + l31) * PADK + koff];
      bf16x8 b0 = *(const bf16x8*)&Tb[((w & 1) * 64 + l31) * PADK + koff];
      bf16x8 b1 = *(const bf16x8*)&Tb[((w & 1) * 64 + 32 + l31) * PADK + koff];
      acc[0][0] = __builtin_amdgcn_mfma_f32_32x32x16_bf16(a0, b0, acc[0][0], 0, 0, 0);
      acc[0][1] = __builtin_amdgcn_mfma_f32_32x32x16_bf16(a0, b1, acc[0][1], 0, 0, 0);
      acc[1][0] = __builtin_amdgcn_mfma_f32_32x32x16_bf16(a1, b0, acc[1][0], 0, 0, 0);
      acc[1][1] = __builtin_amdgcn_mfma_f32_32x32x16_bf16(a1, b1, acc[1][1], 0, 0, 0);
    }
  }
  float* G = ws + W_G + ((size_t)mvar * 36 + blockIdx.x) * 16384;
#pragma unroll
  for (int fi = 0; fi < 2; ++fi)
#pragma unroll
    for (int fj = 0; fj < 2; ++fj)
#pragma unroll
      for (int v = 0; v < 16; ++v) {
        const int il = (w >> 1) * 64 + fi * 32 + (v & 3) + ((v >> 2) << 3) + (hw << 2);
        const int jl = (w & 1) * 64 + fj * 32 + l31;
        atomicAdd(&G[il * 128 + jl], acc[fi][fj][v]);
      }
}

// ---------- K6b: centered off-diag cov^2 reduce over Gram tiles ----------
__global__ __launch_bounds__(256) void k6b_covred(float* __restrict__ ws) {
  const int mvar = blockIdx.y;
  int tti = 0, rem = blockIdx.x;
  while (rem >= 8 - tti) { rem -= 8 - tti; ++tti; }
  const int ttj = tti + rem;
  const int i0 = tti * 128, j0 = ttj * 128;
  const float* G = ws + W_G + ((size_t)mvar * 36 + blockIdx.x) * 16384;
  const float* cs = ws + W_CSUM + mvar * C;
  const int t = threadIdx.x;
  float lsum = 0.f;
  for (int i = 0; i < 64; ++i) {
    int e = i * 256 + t;
    int r = e >> 7, c = e & 127;
    int gi = i0 + r, gj = j0 + c;
    if (gi != gj) {
      float mui = cs[gi] * (1.f / 5120.f);
      float muj = cs[gj] * (1.f / 5120.f);
      float cv = (G[e] - 5120.f * mui * muj) * (1.f / 5119.f);
      lsum += cv * cv;
    }
  }
  lsum *= (tti == ttj) ? 1.f : 2.f;
  float s = block_reduce_sum(lsum);
  if (t == 0) atomicAdd(&ws[W_SCAL + S_COVL], s);
}

// ---------- K7: final combine ----------
__global__ __launch_bounds__(256) void k7_final(float* __restrict__ ws, float* __restrict__ out) {
  const int t = threadIdx.x;
  float rl = 0.f;
  for (int i = t; i < 8 * C; i += 256) {
    float s = ws[W_CSUM + i], q = ws[W_CSSQ + i];
    float var = (q - s * s * (1.f / 5120.f)) * (1.f / 5119.f);
    rl += fmaxf(0.f, 1.f - sqrtf(var + KEPS));
  }
  float varL = block_reduce_sum(rl);
  if (t == 0) {
    float invG = ws[W_SCAL + S_INVG] * (1.f / (256.f * 8192.f));
    float varG = ws[W_SCAL + S_VARG] * (1.f / 8192.f);
    float covG =
        (ws[W_SCAL + S_PSUM] * (1.f / (255.f * 255.f)) - ws[W_SCAL + S_DSQG]) * (1.f / 8192.f);
    float g = KLAMBDA * invG + KMU * 0.5f * varG + KNU * covG;
    float invL = ws[W_SCAL + S_INVL] * (1.f / ((float)NP * (float)C));
    float l = 0.5f * (KLAMBDA * invL + KMU * 0.5f * varL * (1.f / 1024.f) +
                      KNU * ws[W_SCAL + S_COVL] * (1.f / 1024.f));
    out[0] = KALPHA * g + (1.f - KALPHA) * l;
  }
}

extern "C" void kernel_launch(void* const* d_in, const int* in_sizes, int n_in,
                              void* d_out, int out_size, void* d_ws, size_t ws_size,
                              hipStream_t stream) {
  (void)in_sizes; (void)n_in; (void)out_size; (void)ws_size;
  const float* zg0 = (const float*)d_in[0];
  const float* zg1 = (const float*)d_in[1];
  const float* zl0 = (const float*)d_in[2];
  const float* zl1 = (const float*)d_in[3];
  const float* gr0 = (const float*)d_in[4];
  const float* gr1 = (const float*)d_in[5];
  float* ws = (float*)d_ws;
  float* out = (float*)d_out;

  hipMemsetAsync(d_ws, 0, (size_t)W_END * 4, stream);
  hipLaunchKernelGGL(k1a_gstats, dim3(32, 8), dim3(256), 0, stream, zg0, zg1, ws);
  hipLaunchKernelGGL(k1b_gfinal, dim3(32), dim3(256), 0, stream, ws);
  hipLaunchKernelGGL(k2_ggram, dim3(4, 32, 2), dim3(256), 0, stream, zg0, zg1, ws);
  hipLaunchKernelGGL(k2b_psum, dim3(128), dim3(256), 0, stream, ws);
  hipLaunchKernelGGL(k3_dist, dim3(4, 256), dim3(256), 0, stream, zl0, zl1, ws);
  hipLaunchKernelGGL(k4_select, dim3(256), dim3(256), 0, stream, gr0, gr1, ws);
  hipLaunchKernelGGL(k5_pairstats, dim3(40, 4), dim3(256), 0, stream, zl0, zl1, ws);
  hipLaunchKernelGGL(k6a_gram, dim3(36, 8, 2), dim3(256), 0, stream, zl0, zl1, ws);
  hipLaunchKernelGGL(k6b_covred, dim3(36, 8), dim3(256), 0, stream, ws);
  hipLaunchKernelGGL(k7_final, dim3(1), dim3(256), 0, stream, ws, out);
}